// Round 11
// baseline (7499.582 us; speedup 1.0000x reference)
//
#include <hip/hip_runtime.h>
#include <hip/hip_bf16.h>
#include <math.h>

// Problem dims
#define BB 16
#define NN 25
#define VV 10000
#define WD 512
#define HD 512
#define ZD 64
#define SDIM 256
#define TT 60
#define NTS 30
#define SSYM 90          // S = NT + T
#define S2 8100          // S*S
#define NEGV -1000000000.0f

// ---------------------------------------------------------------- embedding
__global__ void k_emb(const int* __restrict__ x, const float* __restrict__ enc_emb,
                      float* __restrict__ emb) {
    int i = blockIdx.x * 256 + threadIdx.x;           // 400*512
    if (i >= 400 * 512) return;
    int r = i >> 9, k = i & 511;
    emb[i] = enc_emb[(size_t)x[r] * 512 + k];
}

// ---------------------------------------------------------------- generic fp32 GEMM (float4 LDS)
// C = act(A@B + bias) (+ res).  A: MxK, B: KxN row-major. K % 16 == 0 (and %4).
__global__ __launch_bounds__(256) void gemm_f32(const float* __restrict__ A,
    const float* __restrict__ Bm, const float* __restrict__ bias,
    const float* __restrict__ res, float* __restrict__ C,
    int M, int Nn, int K, int do_relu)
{
    __shared__ float As[16][68];   // 68-stride: 16B-aligned rows, cheap banks
    __shared__ float Bs[16][68];
    int tid = threadIdx.x;
    int tx = tid & 15, ty = tid >> 4;
    int bm = blockIdx.y * 64, bn = blockIdx.x * 64;
    int mm = tid >> 2, l4 = (tid & 3) * 4;   // A stage: row mm, k-quad l4
    int kb = tid >> 4, nn = (tid & 15) * 4;  // B stage: k-row kb, col-quad nn
    bool bfull = (bn + 64 <= Nn);
    float acc[4][4] = {};
    for (int k0 = 0; k0 < K; k0 += 16) {
        float4 a4 = make_float4(0.f, 0.f, 0.f, 0.f);
        if (bm + mm < M) a4 = *(const float4*)&A[(size_t)(bm + mm) * K + k0 + l4];
        As[l4 + 0][mm] = a4.x; As[l4 + 1][mm] = a4.y;
        As[l4 + 2][mm] = a4.z; As[l4 + 3][mm] = a4.w;
        float4 b4;
        if (bfull) {
            b4 = *(const float4*)&Bm[(size_t)(k0 + kb) * Nn + bn + nn];
        } else {
            const float* br = &Bm[(size_t)(k0 + kb) * Nn];
            b4.x = (bn + nn + 0 < Nn) ? br[bn + nn + 0] : 0.f;
            b4.y = (bn + nn + 1 < Nn) ? br[bn + nn + 1] : 0.f;
            b4.z = (bn + nn + 2 < Nn) ? br[bn + nn + 2] : 0.f;
            b4.w = (bn + nn + 3 < Nn) ? br[bn + nn + 3] : 0.f;
        }
        *(float4*)&Bs[kb][nn] = b4;
        __syncthreads();
#pragma unroll
        for (int kk = 0; kk < 16; ++kk) {
            float4 av = *(const float4*)&As[kk][ty * 4];
            float4 bv = *(const float4*)&Bs[kk][tx * 4];
            float avf[4] = {av.x, av.y, av.z, av.w};
            float bvf[4] = {bv.x, bv.y, bv.z, bv.w};
#pragma unroll
            for (int i = 0; i < 4; ++i)
#pragma unroll
                for (int j = 0; j < 4; ++j) acc[i][j] += avf[i] * bvf[j];
        }
        __syncthreads();
    }
#pragma unroll
    for (int i = 0; i < 4; ++i) {
        int r = bm + ty * 4 + i;
        if (r >= M) continue;
#pragma unroll
        for (int j = 0; j < 4; ++j) {
            int cc = bn + tx * 4 + j;
            if (cc >= Nn) continue;
            float v = acc[i][j] + (bias ? bias[cc] : 0.f);
            if (do_relu) v = fmaxf(v, 0.f);
            if (res) v += res[(size_t)r * Nn + cc];
            C[(size_t)r * Nn + cc] = v;
        }
    }
}

// ---------------------------------------------------------------- LSTM
__global__ void k_lstm_init(float* hbuf, float* cbuf, float* hmax) {
    int i = blockIdx.x * 256 + threadIdx.x;
    if (i < 32768) hbuf[i] = 0.f;
    if (i < 16384) cbuf[i] = 0.f;
    if (i < 16384) hmax[i] = -3.0e38f;
}

// gp partials: [(d*16+b)*2048 + col]*8 + kc.  grid 128: (d,kc,cb) = (2,8,8)
__global__ __launch_bounds__(256) void k_lstm_gates(const float* __restrict__ whh_f,
    const float* __restrict__ whh_b, const float* __restrict__ hbuf,
    float* __restrict__ gp, int t)
{
    int blk = blockIdx.x;
    int d = blk >> 6, kc = (blk >> 3) & 7, cb = blk & 7;
    const float* whh = d ? whh_b : whh_f;
    int pp = t & 1;
    const float* hp = hbuf + d * 16384 + pp * 8192;
    __shared__ float hs[16][64];
    for (int i = threadIdx.x; i < 1024; i += 256) {
        int b = i >> 6, k = i & 63;
        hs[b][k] = hp[b * 512 + kc * 64 + k];
    }
    __syncthreads();
    int col = cb * 256 + threadIdx.x;
    float acc[16];
#pragma unroll
    for (int b = 0; b < 16; ++b) acc[b] = 0.f;
    const float* wp = whh + (size_t)(kc * 64) * 2048 + col;
    for (int k = 0; k < 64; ++k) {
        float w = wp[(size_t)k * 2048];
#pragma unroll
        for (int b = 0; b < 16; ++b) acc[b] += w * hs[b][k];
    }
#pragma unroll
    for (int b = 0; b < 16; ++b)
        gp[((size_t)(d * 16 + b) * 2048 + col) * 8 + kc] = acc[b];
}

__global__ __launch_bounds__(256) void k_lstm_update(const float* __restrict__ xg_f,
    const float* __restrict__ xg_b, const float* __restrict__ gp,
    float* __restrict__ hbuf, float* __restrict__ cbuf, float* __restrict__ hmax, int t)
{
    int gid = blockIdx.x * 256 + threadIdx.x;   // 16384
    int d = gid >> 13, r = gid & 8191;
    int b = r >> 9, m = r & 511;
    int tt = d ? (24 - t) : t;
    const float* xg = d ? xg_b : xg_f;
    const float* xr = xg + (size_t)(b * 25 + tt) * 2048;
    float g4[4];
#pragma unroll
    for (int q = 0; q < 4; ++q) {
        int col = q * 512 + m;
        float s = xr[col];
        const float* pp = gp + ((size_t)(d * 16 + b) * 2048 + col) * 8;
#pragma unroll
        for (int kc = 0; kc < 8; ++kc) s += pp[kc];
        g4[q] = s;
    }
    float si = 1.f / (1.f + expf(-g4[0]));
    float sf = 1.f / (1.f + expf(-g4[1]));
    float tg = tanhf(g4[2]);
    float so = 1.f / (1.f + expf(-g4[3]));
    float* c = cbuf + d * 8192;
    float cc = sf * c[r] + si * tg;
    float hh = so * tanhf(cc);
    c[r] = cc;
    hbuf[d * 16384 + ((t & 1) ^ 1) * 8192 + r] = hh;
    float* hm = hmax + b * 1024 + d * 512 + m;
    *hm = fmaxf(*hm, hh);
}

// ---------------------------------------------------------------- encoder head: params, kl, z
__global__ __launch_bounds__(128) void k_encoder(const float* __restrict__ hmax,
    const float* __restrict__ encp_w, const float* __restrict__ encp_b,
    const float* __restrict__ eps, float* __restrict__ z, float* __restrict__ outp)
{
    int b = blockIdx.x, j = threadIdx.x;
    __shared__ float hrow[1024];
    for (int i = j; i < 1024; i += 128) hrow[i] = hmax[b * 1024 + i];
    __syncthreads();
    float dot = encp_b[j];
    for (int k = 0; k < 1024; ++k) dot += hrow[k] * encp_w[(size_t)k * 128 + j];
    __shared__ float prm[128];
    prm[j] = dot;
    __syncthreads();
    __shared__ float red[64];
    if (j < 64) {
        float mean = prm[j], lv = prm[64 + j];
        z[b * 64 + j] = expf(0.5f * lv) * eps[b * 64 + j] + mean;
        red[j] = -0.5f * (lv - mean * mean - expf(lv) + 1.f);
    }
    __syncthreads();
    if (j == 0) {
        float s = 0.f;
        for (int q = 0; q < 64; ++q) s += red[q];
        outp[16 + b] = s;           // kl output
    }
}

// ---------------------------------------------------------------- input builders
__global__ void k_tin(const float* __restrict__ t_emb, const float* __restrict__ z,
                      float* __restrict__ tin) {
    int i = blockIdx.x * 256 + threadIdx.x;
    if (i >= 960 * 320) return;
    int r = i / 320, k = i % 320;
    int b = r / 60, t = r % 60;
    tin[i] = (k < 256) ? t_emb[t * 256 + k] : z[b * 64 + (k - 256)];
}
__global__ void k_ntin(const float* __restrict__ nt_emb, const float* __restrict__ z,
                       float* __restrict__ ntin) {
    int i = blockIdx.x * 256 + threadIdx.x;
    if (i >= 480 * 320) return;
    int r = i / 320, k = i % 320;
    int b = r / 30, nt = r % 30;
    ntin[i] = (k < 256) ? nt_emb[nt * 256 + k] : z[b * 64 + (k - 256)];
}

// ---------------------------------------------------------------- vocab final: GEMM + LSE partials + unary gather
__global__ __launch_bounds__(256) void k_vocab_final(const float* __restrict__ A,
    const float* __restrict__ Bm, const float* __restrict__ bias, const int* __restrict__ x,
    float* __restrict__ pmax, float* __restrict__ psum, float* __restrict__ unary)
{
    __shared__ float As[16][68];
    __shared__ float Bs[16][68];
    __shared__ int xs[400];
    int tid = threadIdx.x;
    for (int i = tid; i < 400; i += 256) xs[i] = x[i];
    int tx = tid & 15, ty = tid >> 4;
    int bm = blockIdx.y * 64, bn = blockIdx.x * 64;
    int mm = tid >> 2, l4 = (tid & 3) * 4;
    int kb = tid >> 4, nn = (tid & 15) * 4;
    bool bfull = (bn + 64 <= VV);
    float acc[4][4] = {};
    for (int k0 = 0; k0 < 256; k0 += 16) {
        float4 a4 = *(const float4*)&A[(size_t)(bm + mm) * 256 + k0 + l4];  // M=960 exact
        As[l4 + 0][mm] = a4.x; As[l4 + 1][mm] = a4.y;
        As[l4 + 2][mm] = a4.z; As[l4 + 3][mm] = a4.w;
        float4 b4;
        if (bfull) {
            b4 = *(const float4*)&Bm[(size_t)(k0 + kb) * VV + bn + nn];
        } else {
            const float* br = &Bm[(size_t)(k0 + kb) * VV];
            b4.x = (bn + nn + 0 < VV) ? br[bn + nn + 0] : 0.f;
            b4.y = (bn + nn + 1 < VV) ? br[bn + nn + 1] : 0.f;
            b4.z = (bn + nn + 2 < VV) ? br[bn + nn + 2] : 0.f;
            b4.w = (bn + nn + 3 < VV) ? br[bn + nn + 3] : 0.f;
        }
        *(float4*)&Bs[kb][nn] = b4;
        __syncthreads();
#pragma unroll
        for (int kk = 0; kk < 16; ++kk) {
            float4 av = *(const float4*)&As[kk][ty * 4];
            float4 bv = *(const float4*)&Bs[kk][tx * 4];
            float avf[4] = {av.x, av.y, av.z, av.w};
            float bvf[4] = {bv.x, bv.y, bv.z, bv.w};
#pragma unroll
            for (int i = 0; i < 4; ++i)
#pragma unroll
                for (int j = 0; j < 4; ++j) acc[i][j] += avf[i] * bvf[j];
        }
        __syncthreads();
    }
    __shared__ float rmax[64][17];
    __shared__ float rsum[64][17];
#pragma unroll
    for (int i = 0; i < 4; ++i) {
        int r = bm + ty * 4 + i;
        int b = r / 60, t = r % 60;
        float vv[4];
        float lm = -3.0e38f;
#pragma unroll
        for (int j = 0; j < 4; ++j) {
            int cc = bn + tx * 4 + j;
            if (cc < VV) { float v = acc[i][j] + bias[cc]; vv[j] = v; lm = fmaxf(lm, v); }
            else vv[j] = -3.0e38f;
        }
        float ls = 0.f;
#pragma unroll
        for (int j = 0; j < 4; ++j)
            if (bn + tx * 4 + j < VV) ls += expf(vv[j] - lm);
        rmax[ty * 4 + i][tx] = lm;
        rsum[ty * 4 + i][tx] = ls;
        // gather unary logits for this sentence's words
#pragma unroll
        for (int j = 0; j < 4; ++j) {
            int cc = bn + tx * 4 + j;
            if (cc < VV) {
                for (int n = 0; n < 25; ++n)
                    if (xs[b * 25 + n] == cc)
                        unary[((size_t)b * 25 + n) * 60 + t] = vv[j];
            }
        }
    }
    __syncthreads();
    if (tid < 64) {
        int row = tid;
        float m = -3.0e38f;
        for (int q = 0; q < 16; ++q) m = fmaxf(m, rmax[row][q]);
        float s = 0.f;
        for (int q = 0; q < 16; ++q) {
            float rm = rmax[row][q];
            if (rm > -1e38f) s += rsum[row][q] * expf(rm - m);
        }
        int r = bm + row;
        pmax[(size_t)r * 157 + blockIdx.x] = m;
        psum[(size_t)r * 157 + blockIdx.x] = s;
    }
}

__global__ void k_vlse(const float* __restrict__ pmax, const float* __restrict__ psum,
                       float* __restrict__ vlse) {
    int r = blockIdx.x * 256 + threadIdx.x;
    if (r >= 960) return;
    float m = -3.0e38f;
    for (int cb = 0; cb < 157; ++cb) m = fmaxf(m, pmax[(size_t)r * 157 + cb]);
    float s = 0.f;
    for (int cb = 0; cb < 157; ++cb) {
        float rm = pmax[(size_t)r * 157 + cb];
        if (rm > -1e38f) s += psum[(size_t)r * 157 + cb] * expf(rm - m);
    }
    vlse[r] = m + logf(s);
}

// ---------------------------------------------------------------- root MLP (tiny), emits raw logits
__global__ __launch_bounds__(256) void k_root(const float* __restrict__ root_emb,
    const float* __restrict__ z, const float* __restrict__ w1, const float* __restrict__ b1,
    const float* __restrict__ resw, const float* __restrict__ resb,
    const float* __restrict__ w2, const float* __restrict__ b2, float* __restrict__ rootlog)
{
    int b = blockIdx.x, j = threadIdx.x;
    __shared__ float h0[320];
    __shared__ float h[256], a[256];
    if (j < 256) h0[j] = root_emb[j];
    if (j < 64)  h0[256 + j] = z[b * 64 + j];
    __syncthreads();
    float d1 = b1[j];
    for (int k = 0; k < 320; ++k) d1 += h0[k] * w1[(size_t)k * 256 + j];
    h[j] = d1;
    for (int l = 0; l < 2; ++l) {
        __syncthreads();
        const float* rw0 = resw + (size_t)(2 * l) * 65536;
        const float* rw1 = resw + (size_t)(2 * l + 1) * 65536;
        float t1 = resb[2 * l * 256 + j];
        for (int k = 0; k < 256; ++k) t1 += h[k] * rw0[(size_t)k * 256 + j];
        a[j] = fmaxf(t1, 0.f);
        __syncthreads();
        float t2 = resb[(2 * l + 1) * 256 + j];
        for (int k = 0; k < 256; ++k) t2 += a[k] * rw1[(size_t)k * 256 + j];
        h[j] = fmaxf(t2, 0.f) + h[j];
    }
    __syncthreads();
    if (j < 30) {
        float d2 = b2[j];
        for (int k = 0; k < 256; ++k) d2 += h[k] * w2[(size_t)k * 30 + j];
        rootlog[b * 30 + j] = d2;
    }
}

// ---------------------------------------------------------------- rule softmax in place (logits -> probs)
__global__ __launch_bounds__(256) void k_rule_softmax(float* __restrict__ rl) {
    int r = blockIdx.x;
    float* row = rl + (size_t)r * S2;
    __shared__ float red[256];
    float m = -3.0e38f;
    for (int i = threadIdx.x; i < S2; i += 256) m = fmaxf(m, row[i]);
    red[threadIdx.x] = m; __syncthreads();
    for (int s = 128; s > 0; s >>= 1) {
        if (threadIdx.x < s) red[threadIdx.x] = fmaxf(red[threadIdx.x], red[threadIdx.x + s]);
        __syncthreads();
    }
    m = red[0];
    __syncthreads();
    float sum = 0.f;
    for (int i = threadIdx.x; i < S2; i += 256) sum += expf(row[i] - m);
    red[threadIdx.x] = sum; __syncthreads();
    for (int s = 128; s > 0; s >>= 1) {
        if (threadIdx.x < s) red[threadIdx.x] += red[threadIdx.x + s];
        __syncthreads();
    }
    float inv = 1.f / red[0];
    __syncthreads();
    for (int i = threadIdx.x; i < S2; i += 256) row[i] = expf(row[i] - m) * inv;
}

// ---------------------------------------------------------------- chart
__global__ void k_chart_fill(float* __restrict__ chart) {
    int i = blockIdx.x * 256 + threadIdx.x;
    if (i < 900000) chart[i] = NEGV;
}
__global__ void k_chart_diag(const float* __restrict__ unary, const float* __restrict__ vlse,
                             float* __restrict__ chart) {
    int idx = blockIdx.x * 256 + threadIdx.x;   // 24000
    if (idx >= 24000) return;
    int b = idx / 1500;
    int rem = idx % 1500;
    int n = rem / 60, t = rem % 60;
    chart[(((size_t)b * 25 + n) * 25 + n) * 90 + 30 + t] = unary[idx] - vlse[b * 60 + t];
}

// ---------------------------------------------------------------- inside: FUSED em+dot+score per width
// EM = exp(m2 - M) built in LDS (per-u shift, exact); 30 rule-dots via wave reduce;
// chart written directly.  Replaces 3 kernels/width with 1.
__global__ __launch_bounds__(256) void k_inside_fused(const float* __restrict__ ruleB,
    float* __restrict__ chart, int w)
{
    int i = blockIdx.x, b = blockIdx.y;
    int wm1 = w - 1;
    __shared__ float EL[24][91], ER[24][91];
    __shared__ float EMs[S2];
    __shared__ float mlu[24], mru[24];
    __shared__ float Msh;
    int total = wm1 * 90;
    for (int idx = threadIdx.x; idx < total; idx += 256) {
        int u = idx / 90, s = idx % 90;
        EL[u][s] = chart[(((size_t)b * 25 + i) * 25 + (i + u)) * 90 + s];
        ER[u][s] = chart[(((size_t)b * 25 + (i + u + 1)) * 25 + (i + w - 1)) * 90 + s];
    }
    __syncthreads();
    if (threadIdx.x < wm1) {
        int u = threadIdx.x;
        float m = -3.0e38f;
        for (int s = 0; s < 90; ++s) m = fmaxf(m, EL[u][s]);
        mlu[u] = m;
    } else if (threadIdx.x >= 64 && threadIdx.x < 64 + wm1) {
        int u = threadIdx.x - 64;
        float m = -3.0e38f;
        for (int s = 0; s < 90; ++s) m = fmaxf(m, ER[u][s]);
        mru[u] = m;
    }
    __syncthreads();
    if (threadIdx.x == 0) {
        float M = -3.0e38f;
        for (int u = 0; u < wm1; ++u) M = fmaxf(M, mlu[u] + mru[u]);
        Msh = M;
    }
    __syncthreads();
    float M = Msh;
    for (int idx = threadIdx.x; idx < total; idx += 256) {
        int u = idx / 90, s = idx % 90;
        EL[u][s] = expf(EL[u][s] + mru[u] - M);   // <= 1
        ER[u][s] = expf(ER[u][s] - mru[u]);       // <= 1
    }
    __syncthreads();
    for (int o = threadIdx.x; o < S2; o += 256) {
        int Bs_ = o / 90, Cs = o % 90;
        float acc = 0.f;
        for (int u = 0; u < wm1; ++u) acc += EL[u][Bs_] * ER[u][Cs];
        EMs[o] = acc;
    }
    __syncthreads();
    // 30 dots: wave wv handles A = wv, wv+4, ...
    int wv = threadIdx.x >> 6, lane = threadIdx.x & 63;
    for (int A = wv; A < 30; A += 4) {
        const float* rb = ruleB + ((size_t)b * 30 + A) * S2;
        float acc = 0.f;
        for (int l = lane; l < S2; l += 64) acc += EMs[l] * rb[l];
#pragma unroll
        for (int off = 32; off > 0; off >>= 1) acc += __shfl_down(acc, off);
        if (lane == 0)
            chart[(((size_t)b * 25 + i) * 25 + (i + w - 1)) * 90 + A] =
                M + logf(fmaxf(acc, 1e-38f));
    }
}

// ---------------------------------------------------------------- final: -logZ with root log-softmax folded in
__global__ void k_final(const float* __restrict__ rootlog, const float* __restrict__ chart,
                        float* __restrict__ outp) {
    int b = threadIdx.x;
    if (b >= 16) return;
    const float* rl = rootlog + b * 30;
    const float* ch = chart + (((size_t)b * 25 + 0) * 25 + 24) * 90;
    float m1 = -3.0e38f, m2v = -3.0e38f;
    for (int A = 0; A < 30; ++A) {
        m1 = fmaxf(m1, rl[A]);
        m2v = fmaxf(m2v, rl[A] + ch[A]);
    }
    float s1 = 0.f, s2 = 0.f;
    for (int A = 0; A < 30; ++A) {
        s1 += expf(rl[A] - m1);
        s2 += expf(rl[A] + ch[A] - m2v);
    }
    outp[b] = -((m2v + logf(s2)) - (m1 + logf(s1)));
}

// ================================================================ launch
extern "C" void kernel_launch(void* const* d_in, const int* in_sizes, int n_in,
                              void* d_out, int out_size, void* d_ws, size_t ws_size,
                              hipStream_t stream)
{
    const int*   x        = (const int*)  d_in[0];
    const float* eps      = (const float*)d_in[1];
    const float* enc_emb  = (const float*)d_in[2];
    const float* f_wih    = (const float*)d_in[3];
    const float* f_whh    = (const float*)d_in[4];
    const float* f_bb     = (const float*)d_in[5];
    const float* b_wih    = (const float*)d_in[6];
    const float* b_whh    = (const float*)d_in[7];
    const float* b_bb     = (const float*)d_in[8];
    const float* encp_w   = (const float*)d_in[9];
    const float* encp_b   = (const float*)d_in[10];
    const float* t_emb    = (const float*)d_in[11];
    const float* nt_emb   = (const float*)d_in[12];
    const float* root_emb = (const float*)d_in[13];
    const float* rule_w   = (const float*)d_in[14];
    const float* rule_bi  = (const float*)d_in[15];
    const float* root_w1  = (const float*)d_in[16];
    const float* root_b1  = (const float*)d_in[17];
    const float* root_rw  = (const float*)d_in[18];
    const float* root_rb  = (const float*)d_in[19];
    const float* root_w2  = (const float*)d_in[20];
    const float* root_b2  = (const float*)d_in[21];
    const float* voc_w1   = (const float*)d_in[22];
    const float* voc_b1   = (const float*)d_in[23];
    const float* voc_rw   = (const float*)d_in[24];
    const float* voc_rb   = (const float*)d_in[25];
    const float* voc_w2   = (const float*)d_in[26];
    const float* voc_b2   = (const float*)d_in[27];
    float* out = (float*)d_out;

    float* Wp = (float*)d_ws;
    size_t o = 0;
    float* emb   = Wp + o; o += 400 * 512;
    float* xg_f  = Wp + o; o += 400 * 2048;
    float* xg_b  = Wp + o; o += 400 * 2048;
    float* hbuf  = Wp + o; o += 2 * 2 * 8192;       // [dir][pp][b*512+m]
    float* cbuf  = Wp + o; o += 2 * 8192;
    float* hmax  = Wp + o; o += 16384;              // [b*1024 + dir*512 + m]
    float* gp    = Wp + o; o += 2 * 16 * 2048 * 8;  // lstm split-K partials
    float* z     = Wp + o; o += 1024;
    float* tin   = Wp + o; o += 960 * 320;
    float* ntin  = Wp + o; o += 480 * 320;
    float* mlpH  = Wp + o; o += 960 * 256;
    float* mlpA  = Wp + o; o += 960 * 256;
    float* mlpH2 = Wp + o; o += 960 * 256;
    float* pmax  = Wp + o; o += 960 * 157;
    float* psum  = Wp + o; o += 960 * 157;
    float* vlse  = Wp + o; o += 960;
    float* unary = Wp + o; o += 24000;
    float* ruleB = Wp + o; o += 480 * S2;           // logits -> softmax probs in place
    float* rootlog = Wp + o; o += 480;
    float* chart = Wp + o; o += 900000;

    // encoder
    k_emb<<<800, 256, 0, stream>>>(x, enc_emb, emb);
    gemm_f32<<<dim3(32, 7), 256, 0, stream>>>(emb, f_wih, f_bb, nullptr, xg_f, 400, 2048, 512, 0);
    gemm_f32<<<dim3(32, 7), 256, 0, stream>>>(emb, b_wih, b_bb, nullptr, xg_b, 400, 2048, 512, 0);
    k_lstm_init<<<128, 256, 0, stream>>>(hbuf, cbuf, hmax);
    for (int t = 0; t < 25; ++t) {
        k_lstm_gates<<<128, 256, 0, stream>>>(f_whh, b_whh, hbuf, gp, t);
        k_lstm_update<<<64, 256, 0, stream>>>(xg_f, xg_b, gp, hbuf, cbuf, hmax, t);
    }
    k_encoder<<<16, 128, 0, stream>>>(hmax, encp_w, encp_b, eps, z, out);

    // heads
    k_tin<<<1200, 256, 0, stream>>>(t_emb, z, tin);
    k_ntin<<<600, 256, 0, stream>>>(nt_emb, z, ntin);
    gemm_f32<<<dim3(4, 15), 256, 0, stream>>>(tin, voc_w1, voc_b1, nullptr, mlpH, 960, 256, 320, 0);
    gemm_f32<<<dim3(4, 15), 256, 0, stream>>>(mlpH, voc_rw, voc_rb, nullptr, mlpA, 960, 256, 256, 1);
    gemm_f32<<<dim3(4, 15), 256, 0, stream>>>(mlpA, voc_rw + 65536, voc_rb + 256, mlpH, mlpH2, 960, 256, 256, 1);
    gemm_f32<<<dim3(4, 15), 256, 0, stream>>>(mlpH2, voc_rw + 131072, voc_rb + 512, nullptr, mlpA, 960, 256, 256, 1);
    gemm_f32<<<dim3(4, 15), 256, 0, stream>>>(mlpA, voc_rw + 196608, voc_rb + 768, mlpH2, mlpH, 960, 256, 256, 1);
    k_vocab_final<<<dim3(157, 15), 256, 0, stream>>>(mlpH, voc_w2, voc_b2, x, pmax, psum, unary);
    k_vlse<<<4, 256, 0, stream>>>(pmax, psum, vlse);
    k_root<<<16, 256, 0, stream>>>(root_emb, z, root_w1, root_b1, root_rw, root_rb, root_w2, root_b2, rootlog);
    gemm_f32<<<dim3(127, 8), 256, 0, stream>>>(ntin, rule_w, rule_bi, nullptr, ruleB, 480, S2, 320, 0);
    k_rule_softmax<<<480, 256, 0, stream>>>(ruleB);

    // inside algorithm (fused: 1 kernel per width)
    k_chart_fill<<<(900000 + 255) / 256, 256, 0, stream>>>(chart);
    k_chart_diag<<<(24000 + 255) / 256, 256, 0, stream>>>(unary, vlse, chart);
    for (int w = 2; w <= 25; ++w) {
        int npos = 26 - w;
        k_inside_fused<<<dim3(npos, 16), 256, 0, stream>>>(ruleB, chart, w);
    }
    k_final<<<1, 64, 0, stream>>>(rootlog, chart, out);
}

// Round 12
// 1843.341 us; speedup vs baseline: 4.0685x; 4.0685x over previous
//
#include <hip/hip_runtime.h>
#include <hip/hip_bf16.h>
#include <math.h>

// Problem dims
#define BB 16
#define NN 25
#define VV 10000
#define WD 512
#define HD 512
#define ZD 64
#define SDIM 256
#define TT 60
#define NTS 30
#define SSYM 90          // S = NT + T
#define S2 8100          // S*S
#define NEGV -1000000000.0f

// ---------------------------------------------------------------- embedding
__global__ void k_emb(const int* __restrict__ x, const float* __restrict__ enc_emb,
                      float* __restrict__ emb) {
    int i = blockIdx.x * 256 + threadIdx.x;           // 400*512
    if (i >= 400 * 512) return;
    int r = i >> 9, k = i & 511;
    emb[i] = enc_emb[(size_t)x[r] * 512 + k];
}

// ---------------------------------------------------------------- generic fp32 GEMM (float4 LDS)
// C = act(A@B + bias) (+ res).  A: MxK, B: KxN row-major. K % 16 == 0 (and %4).
__global__ __launch_bounds__(256) void gemm_f32(const float* __restrict__ A,
    const float* __restrict__ Bm, const float* __restrict__ bias,
    const float* __restrict__ res, float* __restrict__ C,
    int M, int Nn, int K, int do_relu)
{
    __shared__ float As[16][68];   // 68-stride: 16B-aligned rows, cheap banks
    __shared__ float Bs[16][68];
    int tid = threadIdx.x;
    int tx = tid & 15, ty = tid >> 4;
    int bm = blockIdx.y * 64, bn = blockIdx.x * 64;
    int mm = tid >> 2, l4 = (tid & 3) * 4;   // A stage: row mm, k-quad l4
    int kb = tid >> 4, nn = (tid & 15) * 4;  // B stage: k-row kb, col-quad nn
    bool bfull = (bn + 64 <= Nn);
    float acc[4][4] = {};
    for (int k0 = 0; k0 < K; k0 += 16) {
        float4 a4 = make_float4(0.f, 0.f, 0.f, 0.f);
        if (bm + mm < M) a4 = *(const float4*)&A[(size_t)(bm + mm) * K + k0 + l4];
        As[l4 + 0][mm] = a4.x; As[l4 + 1][mm] = a4.y;
        As[l4 + 2][mm] = a4.z; As[l4 + 3][mm] = a4.w;
        float4 b4;
        if (bfull) {
            b4 = *(const float4*)&Bm[(size_t)(k0 + kb) * Nn + bn + nn];
        } else {
            const float* br = &Bm[(size_t)(k0 + kb) * Nn];
            b4.x = (bn + nn + 0 < Nn) ? br[bn + nn + 0] : 0.f;
            b4.y = (bn + nn + 1 < Nn) ? br[bn + nn + 1] : 0.f;
            b4.z = (bn + nn + 2 < Nn) ? br[bn + nn + 2] : 0.f;
            b4.w = (bn + nn + 3 < Nn) ? br[bn + nn + 3] : 0.f;
        }
        *(float4*)&Bs[kb][nn] = b4;
        __syncthreads();
#pragma unroll
        for (int kk = 0; kk < 16; ++kk) {
            float4 av = *(const float4*)&As[kk][ty * 4];
            float4 bv = *(const float4*)&Bs[kk][tx * 4];
            float avf[4] = {av.x, av.y, av.z, av.w};
            float bvf[4] = {bv.x, bv.y, bv.z, bv.w};
#pragma unroll
            for (int i = 0; i < 4; ++i)
#pragma unroll
                for (int j = 0; j < 4; ++j) acc[i][j] += avf[i] * bvf[j];
        }
        __syncthreads();
    }
#pragma unroll
    for (int i = 0; i < 4; ++i) {
        int r = bm + ty * 4 + i;
        if (r >= M) continue;
#pragma unroll
        for (int j = 0; j < 4; ++j) {
            int cc = bn + tx * 4 + j;
            if (cc >= Nn) continue;
            float v = acc[i][j] + (bias ? bias[cc] : 0.f);
            if (do_relu) v = fmaxf(v, 0.f);
            if (res) v += res[(size_t)r * Nn + cc];
            C[(size_t)r * Nn + cc] = v;
        }
    }
}

// ---------------------------------------------------------------- LSTM
__global__ void k_lstm_init(float* hbuf, float* cbuf, float* hmax) {
    int i = blockIdx.x * 256 + threadIdx.x;
    if (i < 32768) hbuf[i] = 0.f;
    if (i < 16384) cbuf[i] = 0.f;
    if (i < 16384) hmax[i] = -3.0e38f;
}

// gp partials: [(d*16+b)*2048 + col]*8 + kc.  grid 128: (d,kc,cb) = (2,8,8)
__global__ __launch_bounds__(256) void k_lstm_gates(const float* __restrict__ whh_f,
    const float* __restrict__ whh_b, const float* __restrict__ hbuf,
    float* __restrict__ gp, int t)
{
    int blk = blockIdx.x;
    int d = blk >> 6, kc = (blk >> 3) & 7, cb = blk & 7;
    const float* whh = d ? whh_b : whh_f;
    int pp = t & 1;
    const float* hp = hbuf + d * 16384 + pp * 8192;
    __shared__ float hs[16][64];
    for (int i = threadIdx.x; i < 1024; i += 256) {
        int b = i >> 6, k = i & 63;
        hs[b][k] = hp[b * 512 + kc * 64 + k];
    }
    __syncthreads();
    int col = cb * 256 + threadIdx.x;
    float acc[16];
#pragma unroll
    for (int b = 0; b < 16; ++b) acc[b] = 0.f;
    const float* wp = whh + (size_t)(kc * 64) * 2048 + col;
    for (int k = 0; k < 64; ++k) {
        float w = wp[(size_t)k * 2048];
#pragma unroll
        for (int b = 0; b < 16; ++b) acc[b] += w * hs[b][k];
    }
#pragma unroll
    for (int b = 0; b < 16; ++b)
        gp[((size_t)(d * 16 + b) * 2048 + col) * 8 + kc] = acc[b];
}

__global__ __launch_bounds__(256) void k_lstm_update(const float* __restrict__ xg_f,
    const float* __restrict__ xg_b, const float* __restrict__ gp,
    float* __restrict__ hbuf, float* __restrict__ cbuf, float* __restrict__ hmax, int t)
{
    int gid = blockIdx.x * 256 + threadIdx.x;   // 16384
    int d = gid >> 13, r = gid & 8191;
    int b = r >> 9, m = r & 511;
    int tt = d ? (24 - t) : t;
    const float* xg = d ? xg_b : xg_f;
    const float* xr = xg + (size_t)(b * 25 + tt) * 2048;
    float g4[4];
#pragma unroll
    for (int q = 0; q < 4; ++q) {
        int col = q * 512 + m;
        float s = xr[col];
        const float* pp = gp + ((size_t)(d * 16 + b) * 2048 + col) * 8;
#pragma unroll
        for (int kc = 0; kc < 8; ++kc) s += pp[kc];
        g4[q] = s;
    }
    float si = 1.f / (1.f + expf(-g4[0]));
    float sf = 1.f / (1.f + expf(-g4[1]));
    float tg = tanhf(g4[2]);
    float so = 1.f / (1.f + expf(-g4[3]));
    float* c = cbuf + d * 8192;
    float cc = sf * c[r] + si * tg;
    float hh = so * tanhf(cc);
    c[r] = cc;
    hbuf[d * 16384 + ((t & 1) ^ 1) * 8192 + r] = hh;
    float* hm = hmax + b * 1024 + d * 512 + m;
    *hm = fmaxf(*hm, hh);
}

// ---------------------------------------------------------------- encoder head: params, kl, z
__global__ __launch_bounds__(128) void k_encoder(const float* __restrict__ hmax,
    const float* __restrict__ encp_w, const float* __restrict__ encp_b,
    const float* __restrict__ eps, float* __restrict__ z, float* __restrict__ outp)
{
    int b = blockIdx.x, j = threadIdx.x;
    __shared__ float hrow[1024];
    for (int i = j; i < 1024; i += 128) hrow[i] = hmax[b * 1024 + i];
    __syncthreads();
    float dot = encp_b[j];
    for (int k = 0; k < 1024; ++k) dot += hrow[k] * encp_w[(size_t)k * 128 + j];
    __shared__ float prm[128];
    prm[j] = dot;
    __syncthreads();
    __shared__ float red[64];
    if (j < 64) {
        float mean = prm[j], lv = prm[64 + j];
        z[b * 64 + j] = expf(0.5f * lv) * eps[b * 64 + j] + mean;
        red[j] = -0.5f * (lv - mean * mean - expf(lv) + 1.f);
    }
    __syncthreads();
    if (j == 0) {
        float s = 0.f;
        for (int q = 0; q < 64; ++q) s += red[q];
        outp[16 + b] = s;           // kl output
    }
}

// ---------------------------------------------------------------- input builders
__global__ void k_tin(const float* __restrict__ t_emb, const float* __restrict__ z,
                      float* __restrict__ tin) {
    int i = blockIdx.x * 256 + threadIdx.x;
    if (i >= 960 * 320) return;
    int r = i / 320, k = i % 320;
    int b = r / 60, t = r % 60;
    tin[i] = (k < 256) ? t_emb[t * 256 + k] : z[b * 64 + (k - 256)];
}
__global__ void k_ntin(const float* __restrict__ nt_emb, const float* __restrict__ z,
                       float* __restrict__ ntin) {
    int i = blockIdx.x * 256 + threadIdx.x;
    if (i >= 480 * 320) return;
    int r = i / 320, k = i % 320;
    int b = r / 30, nt = r % 30;
    ntin[i] = (k < 256) ? nt_emb[nt * 256 + k] : z[b * 64 + (k - 256)];
}

// ---------------------------------------------------------------- vocab final: GEMM + LSE partials + unary gather
__global__ __launch_bounds__(256) void k_vocab_final(const float* __restrict__ A,
    const float* __restrict__ Bm, const float* __restrict__ bias, const int* __restrict__ x,
    float* __restrict__ pmax, float* __restrict__ psum, float* __restrict__ unary)
{
    __shared__ float As[16][68];
    __shared__ float Bs[16][68];
    __shared__ int xs[400];
    int tid = threadIdx.x;
    for (int i = tid; i < 400; i += 256) xs[i] = x[i];
    int tx = tid & 15, ty = tid >> 4;
    int bm = blockIdx.y * 64, bn = blockIdx.x * 64;
    int mm = tid >> 2, l4 = (tid & 3) * 4;
    int kb = tid >> 4, nn = (tid & 15) * 4;
    bool bfull = (bn + 64 <= VV);
    float acc[4][4] = {};
    for (int k0 = 0; k0 < 256; k0 += 16) {
        float4 a4 = *(const float4*)&A[(size_t)(bm + mm) * 256 + k0 + l4];  // M=960 exact
        As[l4 + 0][mm] = a4.x; As[l4 + 1][mm] = a4.y;
        As[l4 + 2][mm] = a4.z; As[l4 + 3][mm] = a4.w;
        float4 b4;
        if (bfull) {
            b4 = *(const float4*)&Bm[(size_t)(k0 + kb) * VV + bn + nn];
        } else {
            const float* br = &Bm[(size_t)(k0 + kb) * VV];
            b4.x = (bn + nn + 0 < VV) ? br[bn + nn + 0] : 0.f;
            b4.y = (bn + nn + 1 < VV) ? br[bn + nn + 1] : 0.f;
            b4.z = (bn + nn + 2 < VV) ? br[bn + nn + 2] : 0.f;
            b4.w = (bn + nn + 3 < VV) ? br[bn + nn + 3] : 0.f;
        }
        *(float4*)&Bs[kb][nn] = b4;
        __syncthreads();
#pragma unroll
        for (int kk = 0; kk < 16; ++kk) {
            float4 av = *(const float4*)&As[kk][ty * 4];
            float4 bv = *(const float4*)&Bs[kk][tx * 4];
            float avf[4] = {av.x, av.y, av.z, av.w};
            float bvf[4] = {bv.x, bv.y, bv.z, bv.w};
#pragma unroll
            for (int i = 0; i < 4; ++i)
#pragma unroll
                for (int j = 0; j < 4; ++j) acc[i][j] += avf[i] * bvf[j];
        }
        __syncthreads();
    }
    __shared__ float rmax[64][17];
    __shared__ float rsum[64][17];
#pragma unroll
    for (int i = 0; i < 4; ++i) {
        int r = bm + ty * 4 + i;
        int b = r / 60, t = r % 60;
        float vv[4];
        float lm = -3.0e38f;
#pragma unroll
        for (int j = 0; j < 4; ++j) {
            int cc = bn + tx * 4 + j;
            if (cc < VV) { float v = acc[i][j] + bias[cc]; vv[j] = v; lm = fmaxf(lm, v); }
            else vv[j] = -3.0e38f;
        }
        float ls = 0.f;
#pragma unroll
        for (int j = 0; j < 4; ++j)
            if (bn + tx * 4 + j < VV) ls += expf(vv[j] - lm);
        rmax[ty * 4 + i][tx] = lm;
        rsum[ty * 4 + i][tx] = ls;
        // gather unary logits for this sentence's words
#pragma unroll
        for (int j = 0; j < 4; ++j) {
            int cc = bn + tx * 4 + j;
            if (cc < VV) {
                for (int n = 0; n < 25; ++n)
                    if (xs[b * 25 + n] == cc)
                        unary[((size_t)b * 25 + n) * 60 + t] = vv[j];
            }
        }
    }
    __syncthreads();
    if (tid < 64) {
        int row = tid;
        float m = -3.0e38f;
        for (int q = 0; q < 16; ++q) m = fmaxf(m, rmax[row][q]);
        float s = 0.f;
        for (int q = 0; q < 16; ++q) {
            float rm = rmax[row][q];
            if (rm > -1e38f) s += rsum[row][q] * expf(rm - m);
        }
        int r = bm + row;
        pmax[(size_t)r * 157 + blockIdx.x] = m;
        psum[(size_t)r * 157 + blockIdx.x] = s;
    }
}

__global__ void k_vlse(const float* __restrict__ pmax, const float* __restrict__ psum,
                       float* __restrict__ vlse) {
    int r = blockIdx.x * 256 + threadIdx.x;
    if (r >= 960) return;
    float m = -3.0e38f;
    for (int cb = 0; cb < 157; ++cb) m = fmaxf(m, pmax[(size_t)r * 157 + cb]);
    float s = 0.f;
    for (int cb = 0; cb < 157; ++cb) {
        float rm = pmax[(size_t)r * 157 + cb];
        if (rm > -1e38f) s += psum[(size_t)r * 157 + cb] * expf(rm - m);
    }
    vlse[r] = m + logf(s);
}

// ---------------------------------------------------------------- root MLP (tiny), emits raw logits
__global__ __launch_bounds__(256) void k_root(const float* __restrict__ root_emb,
    const float* __restrict__ z, const float* __restrict__ w1, const float* __restrict__ b1,
    const float* __restrict__ resw, const float* __restrict__ resb,
    const float* __restrict__ w2, const float* __restrict__ b2, float* __restrict__ rootlog)
{
    int b = blockIdx.x, j = threadIdx.x;
    __shared__ float h0[320];
    __shared__ float h[256], a[256];
    if (j < 256) h0[j] = root_emb[j];
    if (j < 64)  h0[256 + j] = z[b * 64 + j];
    __syncthreads();
    float d1 = b1[j];
    for (int k = 0; k < 320; ++k) d1 += h0[k] * w1[(size_t)k * 256 + j];
    h[j] = d1;
    for (int l = 0; l < 2; ++l) {
        __syncthreads();
        const float* rw0 = resw + (size_t)(2 * l) * 65536;
        const float* rw1 = resw + (size_t)(2 * l + 1) * 65536;
        float t1 = resb[2 * l * 256 + j];
        for (int k = 0; k < 256; ++k) t1 += h[k] * rw0[(size_t)k * 256 + j];
        a[j] = fmaxf(t1, 0.f);
        __syncthreads();
        float t2 = resb[(2 * l + 1) * 256 + j];
        for (int k = 0; k < 256; ++k) t2 += a[k] * rw1[(size_t)k * 256 + j];
        h[j] = fmaxf(t2, 0.f) + h[j];
    }
    __syncthreads();
    if (j < 30) {
        float d2 = b2[j];
        for (int k = 0; k < 256; ++k) d2 += h[k] * w2[(size_t)k * 30 + j];
        rootlog[b * 30 + j] = d2;
    }
}

// ---------------------------------------------------------------- rule softmax in place (logits -> probs)
__global__ __launch_bounds__(256) void k_rule_softmax(float* __restrict__ rl) {
    int r = blockIdx.x;
    float* row = rl + (size_t)r * S2;
    __shared__ float red[256];
    float m = -3.0e38f;
    for (int i = threadIdx.x; i < S2; i += 256) m = fmaxf(m, row[i]);
    red[threadIdx.x] = m; __syncthreads();
    for (int s = 128; s > 0; s >>= 1) {
        if (threadIdx.x < s) red[threadIdx.x] = fmaxf(red[threadIdx.x], red[threadIdx.x + s]);
        __syncthreads();
    }
    m = red[0];
    __syncthreads();
    float sum = 0.f;
    for (int i = threadIdx.x; i < S2; i += 256) sum += expf(row[i] - m);
    red[threadIdx.x] = sum; __syncthreads();
    for (int s = 128; s > 0; s >>= 1) {
        if (threadIdx.x < s) red[threadIdx.x] += red[threadIdx.x + s];
        __syncthreads();
    }
    float inv = 1.f / red[0];
    __syncthreads();
    for (int i = threadIdx.x; i < S2; i += 256) row[i] = expf(row[i] - m) * inv;
}

// ---------------------------------------------------------------- chart
__global__ void k_chart_fill(float* __restrict__ chart) {
    int i = blockIdx.x * 256 + threadIdx.x;
    if (i < 900000) chart[i] = NEGV;
}
__global__ void k_chart_diag(const float* __restrict__ unary, const float* __restrict__ vlse,
                             float* __restrict__ chart) {
    int idx = blockIdx.x * 256 + threadIdx.x;   // 24000
    if (idx >= 24000) return;
    int b = idx / 1500;
    int rem = idx % 1500;
    int n = rem / 60, t = rem % 60;
    chart[(((size_t)b * 25 + n) * 25 + n) * 90 + 30 + t] = unary[idx] - vlse[b * 60 + t];
}

// ---------------------------------------------------------------- inside: EM = exp(m2 - M), per-u shifted
// m2[B,C] = LSE_u(left[u,B] + right[u,C]).  Factored with PER-U maxes (exact).
__global__ __launch_bounds__(256) void k_inside_em(const float* __restrict__ chart,
    float* __restrict__ EM, float* __restrict__ m2max, int w)
{
    int i = blockIdx.x, b = blockIdx.y;
    int wm1 = w - 1;
    __shared__ float EL[24][91], ER[24][91];
    __shared__ float mlu[24], mru[24];
    __shared__ float Msh;
    int total = wm1 * 90;
    for (int idx = threadIdx.x; idx < total; idx += 256) {
        int u = idx / 90, s = idx % 90;
        EL[u][s] = chart[(((size_t)b * 25 + i) * 25 + (i + u)) * 90 + s];
        ER[u][s] = chart[(((size_t)b * 25 + (i + u + 1)) * 25 + (i + w - 1)) * 90 + s];
    }
    __syncthreads();
    if (threadIdx.x < wm1) {
        int u = threadIdx.x;
        float m = -3.0e38f;
        for (int s = 0; s < 90; ++s) m = fmaxf(m, EL[u][s]);
        mlu[u] = m;
    } else if (threadIdx.x >= 64 && threadIdx.x < 64 + wm1) {
        int u = threadIdx.x - 64;
        float m = -3.0e38f;
        for (int s = 0; s < 90; ++s) m = fmaxf(m, ER[u][s]);
        mru[u] = m;
    }
    __syncthreads();
    if (threadIdx.x == 0) {
        float M = -3.0e38f;
        for (int u = 0; u < wm1; ++u) M = fmaxf(M, mlu[u] + mru[u]);
        Msh = M;
    }
    __syncthreads();
    float M = Msh;
    for (int idx = threadIdx.x; idx < total; idx += 256) {
        int u = idx / 90, s = idx % 90;
        EL[u][s] = expf(EL[u][s] + mru[u] - M);   // <= 1
        ER[u][s] = expf(ER[u][s] - mru[u]);       // <= 1
    }
    __syncthreads();
    float* em = EM + ((size_t)b * 24 + i) * S2;
    for (int o = threadIdx.x; o < S2; o += 256) {
        int Bs = o / 90, Cs = o % 90;
        float acc = 0.f;
        for (int u = 0; u < wm1; ++u) acc += EL[u][Bs] * ER[u][Cs];
        em[o] = acc;
    }
    if (threadIdx.x == 0) m2max[b * 24 + i] = M;
}

// ---------------------------------------------------------------- inside: split-K dots  dot[b,i,A,kc]
// Each block owns a disjoint (b, kc) ruleB slice, reused across all npos positions.
__global__ __launch_bounds__(512) void k_inside_dot(const float* __restrict__ ER,
    const float* __restrict__ EM, float* __restrict__ dotp, int w)
{
    int kc = blockIdx.x, b = blockIdx.y;
    int npos = 26 - w;
    int L = S2 - kc * 256; if (L > 256) L = 256;
    __shared__ float ERs[30][257];
    __shared__ float EMs[24][257];
    for (int idx = threadIdx.x; idx < 30 * L; idx += 512) {
        int A = idx / L, l = idx % L;
        ERs[A][l] = ER[((size_t)b * 30 + A) * S2 + kc * 256 + l];
    }
    for (int idx = threadIdx.x; idx < npos * L; idx += 512) {
        int i = idx / L, l = idx % L;
        EMs[i][l] = EM[((size_t)b * 24 + i) * S2 + kc * 256 + l];
    }
    __syncthreads();
    for (int p = threadIdx.x; p < npos * 30; p += 512) {
        int i = p / 30, A = p % 30;
        float acc = 0.f;
        for (int l = 0; l < L; ++l) acc += EMs[i][l] * ERs[A][l];
        dotp[(((size_t)b * 24 + i) * 30 + A) * 32 + kc] = acc;
    }
}

__global__ void k_inside_score(const float* __restrict__ dotp, const float* __restrict__ m2max,
                               float* __restrict__ chart, int w)
{
    int npos = 26 - w;
    int tot = 16 * npos * 30;
    int p = blockIdx.x * 256 + threadIdx.x;
    if (p >= tot) return;
    int b = p / (npos * 30);
    int rem = p % (npos * 30);
    int i = rem / 30, A = rem % 30;
    const float* dp = dotp + (((size_t)b * 24 + i) * 30 + A) * 32;
    float s = 0.f;
#pragma unroll
    for (int kc = 0; kc < 32; ++kc) s += dp[kc];
    float v = m2max[b * 24 + i] + logf(fmaxf(s, 1e-38f));
    chart[(((size_t)b * 25 + i) * 25 + (i + w - 1)) * 90 + A] = v;
}

// ---------------------------------------------------------------- final: -logZ with root log-softmax folded in
__global__ void k_final(const float* __restrict__ rootlog, const float* __restrict__ chart,
                        float* __restrict__ outp) {
    int b = threadIdx.x;
    if (b >= 16) return;
    const float* rl = rootlog + b * 30;
    const float* ch = chart + (((size_t)b * 25 + 0) * 25 + 24) * 90;
    float m1 = -3.0e38f, m2v = -3.0e38f;
    for (int A = 0; A < 30; ++A) {
        m1 = fmaxf(m1, rl[A]);
        m2v = fmaxf(m2v, rl[A] + ch[A]);
    }
    float s1 = 0.f, s2 = 0.f;
    for (int A = 0; A < 30; ++A) {
        s1 += expf(rl[A] - m1);
        s2 += expf(rl[A] + ch[A] - m2v);
    }
    outp[b] = -((m2v + logf(s2)) - (m1 + logf(s1)));
}

// ================================================================ launch
extern "C" void kernel_launch(void* const* d_in, const int* in_sizes, int n_in,
                              void* d_out, int out_size, void* d_ws, size_t ws_size,
                              hipStream_t stream)
{
    const int*   x        = (const int*)  d_in[0];
    const float* eps      = (const float*)d_in[1];
    const float* enc_emb  = (const float*)d_in[2];
    const float* f_wih    = (const float*)d_in[3];
    const float* f_whh    = (const float*)d_in[4];
    const float* f_bb     = (const float*)d_in[5];
    const float* b_wih    = (const float*)d_in[6];
    const float* b_whh    = (const float*)d_in[7];
    const float* b_bb     = (const float*)d_in[8];
    const float* encp_w   = (const float*)d_in[9];
    const float* encp_b   = (const float*)d_in[10];
    const float* t_emb    = (const float*)d_in[11];
    const float* nt_emb   = (const float*)d_in[12];
    const float* root_emb = (const float*)d_in[13];
    const float* rule_w   = (const float*)d_in[14];
    const float* rule_bi  = (const float*)d_in[15];
    const float* root_w1  = (const float*)d_in[16];
    const float* root_b1  = (const float*)d_in[17];
    const float* root_rw  = (const float*)d_in[18];
    const float* root_rb  = (const float*)d_in[19];
    const float* root_w2  = (const float*)d_in[20];
    const float* root_b2  = (const float*)d_in[21];
    const float* voc_w1   = (const float*)d_in[22];
    const float* voc_b1   = (const float*)d_in[23];
    const float* voc_rw   = (const float*)d_in[24];
    const float* voc_rb   = (const float*)d_in[25];
    const float* voc_w2   = (const float*)d_in[26];
    const float* voc_b2   = (const float*)d_in[27];
    float* out = (float*)d_out;

    float* Wp = (float*)d_ws;
    size_t o = 0;
    float* emb   = Wp + o; o += 400 * 512;
    float* xg_f  = Wp + o; o += 400 * 2048;
    float* xg_b  = Wp + o; o += 400 * 2048;
    float* hbuf  = Wp + o; o += 2 * 2 * 8192;       // [dir][pp][b*512+m]
    float* cbuf  = Wp + o; o += 2 * 8192;
    float* hmax  = Wp + o; o += 16384;              // [b*1024 + dir*512 + m]
    float* gp    = Wp + o; o += 2 * 16 * 2048 * 8;  // lstm split-K partials
    float* z     = Wp + o; o += 1024;
    float* tin   = Wp + o; o += 960 * 320;
    float* ntin  = Wp + o; o += 480 * 320;
    float* mlpH  = Wp + o; o += 960 * 256;
    float* mlpA  = Wp + o; o += 960 * 256;
    float* mlpH2 = Wp + o; o += 960 * 256;
    float* pmax  = Wp + o; o += 960 * 157;
    float* psum  = Wp + o; o += 960 * 157;
    float* vlse  = Wp + o; o += 960;
    float* unary = Wp + o; o += 24000;
    float* ruleB = Wp + o; o += 480 * S2;           // logits -> softmax probs in place
    float* rootlog = Wp + o; o += 480;
    float* chart = Wp + o; o += 900000;
    float* EM    = Wp + o; o += 16 * 24 * S2;
    float* m2m   = Wp + o; o += 16 * 24;
    float* dotp  = Wp + o; o += 16 * 24 * 30 * 32;

    // encoder
    k_emb<<<800, 256, 0, stream>>>(x, enc_emb, emb);
    gemm_f32<<<dim3(32, 7), 256, 0, stream>>>(emb, f_wih, f_bb, nullptr, xg_f, 400, 2048, 512, 0);
    gemm_f32<<<dim3(32, 7), 256, 0, stream>>>(emb, b_wih, b_bb, nullptr, xg_b, 400, 2048, 512, 0);
    k_lstm_init<<<128, 256, 0, stream>>>(hbuf, cbuf, hmax);
    for (int t = 0; t < 25; ++t) {
        k_lstm_gates<<<128, 256, 0, stream>>>(f_whh, b_whh, hbuf, gp, t);
        k_lstm_update<<<64, 256, 0, stream>>>(xg_f, xg_b, gp, hbuf, cbuf, hmax, t);
    }
    k_encoder<<<16, 128, 0, stream>>>(hmax, encp_w, encp_b, eps, z, out);

    // heads
    k_tin<<<1200, 256, 0, stream>>>(t_emb, z, tin);
    k_ntin<<<600, 256, 0, stream>>>(nt_emb, z, ntin);
    gemm_f32<<<dim3(4, 15), 256, 0, stream>>>(tin, voc_w1, voc_b1, nullptr, mlpH, 960, 256, 320, 0);
    gemm_f32<<<dim3(4, 15), 256, 0, stream>>>(mlpH, voc_rw, voc_rb, nullptr, mlpA, 960, 256, 256, 1);
    gemm_f32<<<dim3(4, 15), 256, 0, stream>>>(mlpA, voc_rw + 65536, voc_rb + 256, mlpH, mlpH2, 960, 256, 256, 1);
    gemm_f32<<<dim3(4, 15), 256, 0, stream>>>(mlpH2, voc_rw + 131072, voc_rb + 512, nullptr, mlpA, 960, 256, 256, 1);
    gemm_f32<<<dim3(4, 15), 256, 0, stream>>>(mlpA, voc_rw + 196608, voc_rb + 768, mlpH2, mlpH, 960, 256, 256, 1);
    k_vocab_final<<<dim3(157, 15), 256, 0, stream>>>(mlpH, voc_w2, voc_b2, x, pmax, psum, unary);
    k_vlse<<<4, 256, 0, stream>>>(pmax, psum, vlse);
    k_root<<<16, 256, 0, stream>>>(root_emb, z, root_w1, root_b1, root_rw, root_rb, root_w2, root_b2, rootlog);
    gemm_f32<<<dim3(127, 8), 256, 0, stream>>>(ntin, rule_w, rule_bi, nullptr, ruleB, 480, S2, 320, 0);
    k_rule_softmax<<<480, 256, 0, stream>>>(ruleB);

    // inside algorithm (3-kernel split-K: em -> dot -> score)
    k_chart_fill<<<(900000 + 255) / 256, 256, 0, stream>>>(chart);
    k_chart_diag<<<(24000 + 255) / 256, 256, 0, stream>>>(unary, vlse, chart);
    for (int w = 2; w <= 25; ++w) {
        int npos = 26 - w;
        k_inside_em<<<dim3(npos, 16), 256, 0, stream>>>(chart, EM, m2m, w);
        k_inside_dot<<<dim3(32, 16), 512, 0, stream>>>(ruleB, EM, dotp, w);
        int tot = 16 * npos * 30;
        k_inside_score<<<(tot + 255) / 256, 256, 0, stream>>>(dotp, m2m, chart, w);
    }
    k_final<<<1, 64, 0, stream>>>(rootlog, chart, out);
}